// Round 3
// baseline (111.558 us; speedup 1.0000x reference)
//
#include <hip/hip_runtime.h>
#include <hip/hip_cooperative_groups.h>
#include <math.h>

namespace cg = cooperative_groups;

#define NB    8
#define NPTS  4096
#define NTH   1024
#define NBLK  64
#define SPT   4
#define NFILT 16
#define MAXQ  512
#define MAXU  256
#define MAXK  256

// d_ws layout (~1.3 MB; no initialization required)
#define WS_PCC  0         // u32[8][16] pred active count per 256-chunk
#define WS_TCC  512       // u32[8][16] targ active count per 256-chunk
#define WS_PKEY 1024      // u64[8][4096] pred keys (chunk-local compaction)
#define WS_PPOS 263168    // float4[8][4096] pred pos (normalized) + idx in .w
#define WS_TPOS 787456    // float4[8][4096] targ pos (real) + idx in .w

__device__ __forceinline__ int blockReduceSumI(int v, int* scr, int tid) {
    #pragma unroll
    for (int o = 32; o > 0; o >>= 1) v += __shfl_down(v, o, 64);
    if ((tid & 63) == 0) scr[tid >> 6] = v;
    __syncthreads();
    if (tid == 0) {
        int s = 0;
        #pragma unroll
        for (int w = 0; w < NTH / 64; ++w) s += scr[w];
        scr[16] = s;
    }
    __syncthreads();
    return scr[16];
}

__device__ __forceinline__ float rowAngleDeg(float a0, float a1, float a2,
                                             float b0, float b1, float b2) {
    float dot = a0 * b0 + a1 * b1 + a2 * b2;
    float na = sqrtf(a0 * a0 + a1 * a1 + a2 * a2);
    float nb = sqrtf(b0 * b0 + b1 * b1 + b2 * b2);
    float c = dot / (na * nb);
    c = fminf(1.0f, fmaxf(-1.0f, c));
    return acosf(c) * 57.29577951308232f;  // /pi*180
}

// Cooperative single-kernel. Phase 1: all 64 blocks (1 record/thread) load raw
// tensors at full-ish chip parallelism and write chunk-compacted records to ws.
// Grid sync. Phase 2: blocks 0..7 (one per batch) run NMS fixpoint + matching
// on the compacted (L2/L3-warm) records; the 8-CU phase no longer touches the
// cold 2.6 MB raw input except for a few rotation rows in the epilogue.
__global__ __launch_bounds__(NTH) void molan_coop(const float* __restrict__ pred,
                                                  const float* __restrict__ targ,
                                                  unsigned char* __restrict__ ws,
                                                  float* __restrict__ out) {
    __shared__ int   wcnt[16];
    __shared__ int   scr_i[32];
    __shared__ float scr_f[16];
    __shared__ int   cnt[4];
    __shared__ int   ccP[16], ccT[16];
    __shared__ unsigned long long f_key[NFILT];
    __shared__ float f_x[NFILT], f_y[NFILT], f_z[NFILT];
    __shared__ unsigned long long q_key[MAXQ];
    __shared__ float q_x[MAXQ], q_y[MAXQ], q_z[MAXQ];
    __shared__ int   q_res[MAXQ];
    __shared__ unsigned long long u_key[MAXU];
    __shared__ float u_x[MAXU], u_y[MAXU], u_z[MAXU];
    __shared__ float k_x[MAXK], k_y[MAXK], k_z[MAXK];
    __shared__ int   k_idx[MAXK];
    __shared__ unsigned int k_match[MAXK];

    unsigned int* pcc = (unsigned int*)(ws + WS_PCC);
    unsigned int* tcc = (unsigned int*)(ws + WS_TCC);
    unsigned long long* pkeyw = (unsigned long long*)(ws + WS_PKEY);
    float4* pposw = (float4*)(ws + WS_PPOS);
    float4* tposw = (float4*)(ws + WS_TPOS);

    const int tid = threadIdx.x;

    // ================= Phase 1: full-grid prep (1 record per thread) ========
    {
        const int gid = blockIdx.x * NTH + tid;
        const int tensor = gid >> 15;           // 0 = pred, 1 = targ
        const int batch = (gid >> 12) & 7;
        const int n = gid & 4095;
        const float* base = (tensor ? targ : pred)
                            + (size_t)batch * NPTS * 10 + (size_t)n * 10;
        float2 f0 = *(const float2*)base;         // conf_raw, off_z
        float2 f1 = *(const float2*)(base + 2);   // off_x, off_y
        const float gz = (float)(n >> 10);
        const float gx = (float)((n >> 5) & 31);
        const float gy = (float)(n & 31);

        bool active;
        unsigned long long key = 0;
        float4 rec;
        if (tensor == 0) {
            float conf = 1.0f / (1.0f + expf(-f0.x));   // jax.nn.sigmoid
            active = conf > 0.5f;
            unsigned int u = ~(__float_as_uint(conf) | 0x80000000u);  // conf desc
            key = ((unsigned long long)u << 32) | (unsigned int)n;    // idx asc
            rec = make_float4((f0.y + gz) * 0.25f,
                              (f1.x + gx) * 0.03125f,
                              (f1.y + gy) * 0.03125f,
                              (float)n);
        } else {
            active = f0.x > 0.5f;
            rec = make_float4((f0.y + gz) * 6.25f,      // /4 * 25
                              (f1.x + gx) * 0.78125f,   // /32 * 25
                              (f1.y + gy) * 0.125f,     // /32 * 4
                              (float)n);
        }

        const int lane = tid & 63, wid = tid >> 6;
        unsigned long long ball = __ballot(active);
        int lofs = __popcll(ball & ((1ull << lane) - 1ull));
        if (lane == 0) wcnt[wid] = __popcll(ball);
        __syncthreads();
        int wb = 0;
        for (int w = wid & ~3; w < wid; ++w) wb += wcnt[w];
        const int chunk = n >> 8;
        if ((tid & 255) == 0) {
            int c = wcnt[wid] + wcnt[wid + 1] + wcnt[wid + 2] + wcnt[wid + 3];
            (tensor ? tcc : pcc)[batch * 16 + chunk] = (unsigned int)c;
        }
        if (active) {
            int e = batch * NPTS + chunk * 256 + wb + lofs;
            if (tensor == 0) { pkeyw[e] = key; pposw[e] = rec; }
            else tposw[e] = rec;
        }
    }
    __threadfence();
    cg::this_grid().sync();
    if (blockIdx.x >= NB) return;

    // ================= Phase 2: per-batch NMS + matching (blocks 0..7) ======
    const int b = blockIdx.x;
    const float* pb = pred + (size_t)b * NPTS * 10;
    const float* tb = targ + (size_t)b * NPTS * 10;
    const unsigned long long* pkey_r = pkeyw + b * NPTS;
    const float4* ppos_r = pposw + b * NPTS;
    const float4* tpos_r = tposw + b * NPTS;

    if (tid < 16) ccP[tid] = (int)pcc[b * 16 + tid];
    else if (tid < 32) ccT[tid - 16] = (int)tcc[b * 16 + tid - 16];
    __syncthreads();

    // ---- load compacted records into registers (chunk-local gating) ----
    unsigned long long key[SPT];
    bool  act[SPT];
    int   pidx[SPT];
    float cx[SPT], cy[SPT], cz[SPT];
    #pragma unroll
    for (int s = 0; s < SPT; ++s) {
        int slot = tid + NTH * s;
        bool a = (slot & 255) < ccP[slot >> 8];
        act[s] = a;
        key[s] = ~0ull;
        cx[s] = cy[s] = cz[s] = 0.f; pidx[s] = 0;
        if (a) {
            key[s] = pkey_r[slot];
            float4 p = ppos_r[slot];
            cx[s] = p.x; cy[s] = p.y; cz[s] = p.z; pidx[s] = (int)p.w;
        }
    }
    bool  t_act[SPT];
    int   t_n[SPT];
    float t_x[SPT], t_y[SPT], t_z[SPT];
    #pragma unroll
    for (int s = 0; s < SPT; ++s) {
        int slot = tid + NTH * s;
        bool a = (slot & 255) < ccT[slot >> 8];
        t_act[s] = a;
        t_x[s] = t_y[s] = t_z[s] = 0.f; t_n[s] = 0;
        if (a) {
            float4 p = tpos_r[slot];
            t_x[s] = p.x; t_y[s] = p.y; t_z[s] = p.z; t_n[s] = (int)p.w;
        }
    }

    // ---- NMS fixpoint (exact reference trajectory, order via keys) ----
    int cur = 0;
    #pragma unroll
    for (int c = 0; c < 16; ++c) cur += ccP[c];   // uniform, no barrier
    int prev = -1;
    bool small_done = false;
    int n_pd = 0;
    while (cur != prev) {
        if (cur <= 64) {
            // ---- compact survivors; wave 0 finishes fixpoint in-wave ----
            if (tid == 0) cnt[2] = 0;
            __syncthreads();
            #pragma unroll
            for (int s = 0; s < SPT; ++s) {
                if (act[s]) {
                    int e = atomicAdd(&cnt[2], 1);
                    u_key[e] = key[s]; u_x[e] = cx[s]; u_y[e] = cy[s]; u_z[e] = cz[s];
                }
            }
            __syncthreads();
            if (tid < 64) {
                const int n = cnt[2];   // == cur
                bool va = tid < n;
                unsigned long long k = va ? u_key[tid] : ~0ull;
                float x = va ? u_x[tid] : 0.f;
                float y = va ? u_y[tid] : 0.f;
                float z = va ? u_z[tid] : 0.f;
                bool a = va;
                int pc = prev, cc = cur;
                while (cc != pc) {
                    unsigned long long am = __ballot(a);
                    bool sfl = false;
                    for (int i = 0; i < n; ++i) {
                        unsigned long long ki = __shfl(k, i, 64);
                        float xi = __shfl(x, i, 64);
                        float yi = __shfl(y, i, 64);
                        float zi = __shfl(z, i, 64);
                        if (((am >> i) & 1ull) && ki < k) {
                            float dx = xi - x, dy = yi - y, dz = zi - z;
                            if (dx * dx + dy * dy + dz * dz < 4.0f) sfl = true;
                        }
                    }
                    unsigned long long rm = __ballot(a && !sfl);
                    bool sp = false;
                    for (int i = 0; i < n; ++i) {
                        if ((rm >> i) & 1ull) {
                            unsigned long long ki = __shfl(k, i, 64);
                            float xi = __shfl(x, i, 64);
                            float yi = __shfl(y, i, 64);
                            float zi = __shfl(z, i, 64);
                            if (ki < k) {
                                float dx = xi - x, dy = yi - y, dz = zi - z;
                                if (dx * dx + dy * dy + dz * dz < 4.0f) sp = true;
                            }
                        }
                    }
                    a = a && !sp;
                    pc = cc;
                    cc = __popcll(__ballot(a));
                }
                unsigned long long fm = __ballot(a);
                int K = __popcll(fm);
                if (tid == 0) { cnt[3] = K; cnt[0] = K; }
                if (a) {
                    int e = __popcll(fm & ((1ull << tid) - 1ull));
                    k_x[e] = x * 25.0f; k_y[e] = y * 25.0f; k_z[e] = z * 4.0f;
                    k_idx[e] = (int)(k & 0xFFFFFFFFull);
                    k_match[e] = 0xFFFFFFFFu;
                }
            }
            __syncthreads();
            n_pd = cnt[0];
            small_done = true;
            break;
        }

        // ---- cooperative step (large active set) ----
        {
            unsigned long long bk = ~0ull;
            float bx = 0.f, by = 0.f, bz = 0.f;
            #pragma unroll
            for (int s = 0; s < SPT; ++s)
                if (act[s] && key[s] < bk) { bk = key[s]; bx = cx[s]; by = cy[s]; bz = cz[s]; }
            #pragma unroll
            for (int o = 32; o > 0; o >>= 1) {
                unsigned long long ok = __shfl_xor(bk, o, 64);
                float ox = __shfl_xor(bx, o, 64);
                float oy = __shfl_xor(by, o, 64);
                float oz = __shfl_xor(bz, o, 64);
                if (ok < bk) { bk = ok; bx = ox; by = oy; bz = oz; }
            }
            if ((tid & 63) == 0) {
                int w = tid >> 6;
                f_key[w] = bk; f_x[w] = bx; f_y[w] = by; f_z[w] = bz;
            }
        }
        __syncthreads();

        bool sflag[SPT], pend[SPT];
        #pragma unroll
        for (int s = 0; s < SPT; ++s) {
            sflag[s] = false; pend[s] = false;
            if (!act[s]) continue;
            bool found = false;
            for (int f = 0; f < NFILT; ++f) {
                if (f_key[f] < key[s]) {
                    float dx = f_x[f] - cx[s], dy = f_y[f] - cy[s], dz = f_z[f] - cz[s];
                    if (dx * dx + dy * dy + dz * dz < 4.0f) { found = true; break; }
                }
            }
            if (found) sflag[s] = true;
            else pend[s] = true;
        }
        do {
            if (tid == 0) cnt[1] = 0;
            __syncthreads();
            int qe[SPT];
            #pragma unroll
            for (int s = 0; s < SPT; ++s) {
                qe[s] = -1;
                if (pend[s]) {
                    int e = atomicAdd(&cnt[1], 1);
                    if (e < MAXQ) {
                        q_key[e] = key[s]; q_x[e] = cx[s]; q_y[e] = cy[s]; q_z[e] = cz[s];
                        q_res[e] = 0;
                        qe[s] = e; pend[s] = false;
                    }
                }
            }
            __syncthreads();
            const int Q = min(cnt[1], MAXQ);
            for (int e = 0; e < Q; ++e) {
                unsigned long long qk = q_key[e];
                float qx = q_x[e], qy = q_y[e], qz = q_z[e];
                bool hit = false;
                #pragma unroll
                for (int s = 0; s < SPT; ++s) {
                    if (act[s] && key[s] < qk) {
                        float dx = cx[s] - qx, dy = cy[s] - qy, dz = cz[s] - qz;
                        if (dx * dx + dy * dy + dz * dz < 4.0f) hit = true;
                    }
                }
                if (hit) q_res[e] = 1;
            }
            __syncthreads();
            #pragma unroll
            for (int s = 0; s < SPT; ++s)
                if (qe[s] >= 0) sflag[s] = (q_res[qe[s]] != 0);
        } while (cnt[1] > MAXQ);

        bool upend[SPT], supp[SPT];
        #pragma unroll
        for (int s = 0; s < SPT; ++s) {
            upend[s] = act[s] && !sflag[s];
            supp[s] = false;
        }
        do {
            if (tid == 0) cnt[2] = 0;
            __syncthreads();
            #pragma unroll
            for (int s = 0; s < SPT; ++s) {
                if (upend[s]) {
                    int e = atomicAdd(&cnt[2], 1);
                    if (e < MAXU) {
                        u_key[e] = key[s]; u_x[e] = cx[s]; u_y[e] = cy[s]; u_z[e] = cz[s];
                        upend[s] = false;
                    }
                }
            }
            __syncthreads();
            const int Ku = min(cnt[2], MAXU);
            #pragma unroll
            for (int s = 0; s < SPT; ++s) {
                if (!act[s] || supp[s]) continue;
                for (int e = 0; e < Ku; ++e) {
                    if (u_key[e] < key[s]) {
                        float dx = u_x[e] - cx[s], dy = u_y[e] - cy[s], dz = u_z[e] - cz[s];
                        if (dx * dx + dy * dy + dz * dz < 4.0f) { supp[s] = true; break; }
                    }
                }
            }
        } while (cnt[2] > MAXU);
        int loc = 0;
        #pragma unroll
        for (int s = 0; s < SPT; ++s) {
            if (act[s] && supp[s]) act[s] = false;
            loc += act[s] ? 1 : 0;
        }
        prev = cur;
        cur = blockReduceSumI(loc, scr_i, tid);
    }
    if (!small_done) n_pd = cur;

    // ---- matching: kept preds vs all targets, lowest target idx wins ----
    bool kpend[SPT];
    #pragma unroll
    for (int s = 0; s < SPT; ++s) kpend[s] = small_done ? false : act[s];
    int loc_tp = 0;
    float loc_ang = 0.0f;
    do {
        if (tid == 0 && !small_done) cnt[3] = 0;
        __syncthreads();
        #pragma unroll
        for (int s = 0; s < SPT; ++s) {
            if (kpend[s]) {
                int e = atomicAdd(&cnt[3], 1);
                if (e < MAXK) {
                    k_x[e] = cx[s] * 25.0f; k_y[e] = cy[s] * 25.0f; k_z[e] = cz[s] * 4.0f;
                    k_idx[e] = pidx[s];
                    k_match[e] = 0xFFFFFFFFu;
                    kpend[s] = false;
                }
            }
        }
        __syncthreads();
        const int K = min(cnt[3], MAXK);
        #pragma unroll
        for (int s = 0; s < SPT; ++s) {
            if (!t_act[s]) continue;
            float tx = t_x[s], ty = t_y[s], tz = t_z[s];
            for (int e = 0; e < K; ++e) {
                float dx = tx - k_x[e], dy = ty - k_y[e], dz = tz - k_z[e];
                if (dx * dx + dy * dy + dz * dz < 4.0f)
                    atomicMin(&k_match[e], (unsigned int)t_n[s]);
            }
        }
        __syncthreads();
        if (tid < K) {
            unsigned int m = k_match[tid];
            if (m != 0xFFFFFFFFu) {
                ++loc_tp;
                const float2* pr = (const float2*)(pb + (size_t)k_idx[tid] * 10 + 4);
                float2 p0 = pr[0], p1 = pr[1], p2v = pr[2];
                float ax0 = p0.x, ax1 = p0.y, ax2 = p1.x;
                float ay0 = p1.y, ay1 = p2v.x, ay2 = p2v.y;
                float az0 = ax1 * ay2 - ax2 * ay1;
                float az1 = ax2 * ay0 - ax0 * ay2;
                float az2 = ax0 * ay1 - ax1 * ay0;
                const float2* tr = (const float2*)(tb + (size_t)m * 10 + 4);
                float2 t0 = tr[0], t1 = tr[1], t2v = tr[2];
                float bx0 = t0.x, bx1 = t0.y, bx2 = t1.x;
                float by0 = t1.y, by1 = t2v.x, by2 = t2v.y;
                float bz0 = bx1 * by2 - bx2 * by1;
                float bz1 = bx2 * by0 - bx0 * by2;
                float bz2 = bx0 * by1 - bx1 * by0;
                loc_ang += rowAngleDeg(ax0, ax1, ax2, bx0, bx1, bx2);
                loc_ang += rowAngleDeg(ay0, ay1, ay2, by0, by1, by2);
                loc_ang += rowAngleDeg(az0, az1, az2, bz0, bz1, bz2);
            }
        }
    } while (cnt[3] > MAXK);

    // ---- fused final reduce: tp (int) + angle (float); n_targ from ccT ----
    {
        int v0 = loc_tp;
        float vf = loc_ang;
        #pragma unroll
        for (int o = 32; o > 0; o >>= 1) {
            v0 += __shfl_down(v0, o, 64);
            vf += __shfl_down(vf, o, 64);
        }
        if ((tid & 63) == 0) {
            int w = tid >> 6;
            scr_i[w] = v0; scr_f[w] = vf;
        }
        __syncthreads();
        if (tid == 0) {
            int tp = 0, nt = 0;
            float angsum = 0.0f;
            #pragma unroll
            for (int w = 0; w < NTH / 64; ++w) { tp += scr_i[w]; angsum += scr_f[w]; }
            #pragma unroll
            for (int c = 0; c < 16; ++c) nt += ccT[c];
            out[b * 3 + 0] = (float)tp;
            out[b * 3 + 1] = (float)(n_pd - tp);
            out[b * 3 + 2] = (float)(nt - tp);
            out[NB * 3 + b] = (tp > 0) ? (angsum / (3.0f * (float)tp)) : 0.0f;
        }
    }
}

extern "C" void kernel_launch(void* const* d_in, const int* in_sizes, int n_in,
                              void* d_out, int out_size, void* d_ws, size_t ws_size,
                              hipStream_t stream) {
    const float* pred = (const float*)d_in[0];
    const float* targ = (const float*)d_in[1];
    float* out = (float*)d_out;
    unsigned char* ws = (unsigned char*)d_ws;
    void* args[] = {(void*)&pred, (void*)&targ, (void*)&ws, (void*)&out};
    hipLaunchCooperativeKernel((void*)molan_coop, dim3(NBLK), dim3(NTH), args, 0, stream);
}

// Round 4
// 68.686 us; speedup vs baseline: 1.6242x; 1.6242x over previous
//
#include <hip/hip_runtime.h>
#include <math.h>

#define NB    8
#define NPTS  4096
#define NTH   1024
#define SPT   4
#define NFILT 16
#define MAXQ  512
#define MAXU  256
#define MAXK  256

__device__ __forceinline__ int blockReduceSumI(int v, int* scr, int tid) {
    #pragma unroll
    for (int o = 32; o > 0; o >>= 1) v += __shfl_down(v, o, 64);
    if ((tid & 63) == 0) scr[tid >> 6] = v;
    __syncthreads();
    if (tid == 0) {
        int s = 0;
        #pragma unroll
        for (int w = 0; w < NTH / 64; ++w) s += scr[w];
        scr[16] = s;
    }
    __syncthreads();
    return scr[16];
}

__device__ __forceinline__ float rowAngleDeg(float a0, float a1, float a2,
                                             float b0, float b1, float b2) {
    float dot = a0 * b0 + a1 * b1 + a2 * b2;
    float na = sqrtf(a0 * a0 + a1 * a1 + a2 * a2);
    float nb = sqrtf(b0 * b0 + b1 * b1 + b2 * b2);
    float c = dot / (na * nb);
    c = fminf(1.0f, fmaxf(-1.0f, c));
    return acosf(c) * 57.29577951308232f;  // /pi*180
}

// Fused single-kernel (round-2 structure, reverted from the cooperative
// experiment: cg grid-sync measured 42 us kernel @ 0.5% VALUBusy — dead end).
// All 16 initial global loads are clustered before any arithmetic for max
// memory-level parallelism; NMS fixpoint does one cooperative step while the
// active set is large, then wave 0 finishes in-wave (zero block barriers).
__global__ __launch_bounds__(NTH) void molan_fused(const float* __restrict__ pred,
                                                   const float* __restrict__ targ,
                                                   float* __restrict__ out) {
    __shared__ int   scr_i[32];
    __shared__ float scr_f[16];
    __shared__ int   cnt[4];
    __shared__ unsigned long long f_key[NFILT];
    __shared__ float f_x[NFILT], f_y[NFILT], f_z[NFILT];
    __shared__ unsigned long long q_key[MAXQ];
    __shared__ float q_x[MAXQ], q_y[MAXQ], q_z[MAXQ];
    __shared__ int   q_res[MAXQ];
    __shared__ unsigned long long u_key[MAXU];
    __shared__ float u_x[MAXU], u_y[MAXU], u_z[MAXU];
    __shared__ float k_x[MAXK], k_y[MAXK], k_z[MAXK];
    __shared__ int   k_idx[MAXK];
    __shared__ unsigned int k_match[MAXK];

    const int b = blockIdx.x;
    const int tid = threadIdx.x;
    const float* pb = pred + (size_t)b * NPTS * 10;
    const float* tb = targ + (size_t)b * NPTS * 10;

    // ---- clustered loads: issue all 16 float2 loads before any use ----
    float2 pf0[SPT], pf1[SPT], tf0[SPT], tf1[SPT];
    #pragma unroll
    for (int s = 0; s < SPT; ++s) {
        const int n = tid + NTH * s;
        const float2* p2 = (const float2*)(pb + (size_t)n * 10);
        const float2* t2 = (const float2*)(tb + (size_t)n * 10);
        pf0[s] = p2[0];   // conf_raw, off_z
        pf1[s] = p2[1];   // off_x, off_y
        tf0[s] = t2[0];
        tf1[s] = t2[1];
    }

    unsigned long long key[SPT];
    bool  act[SPT];
    float cx[SPT], cy[SPT], cz[SPT];   // normalized (z/4, x/32, y/32)
    bool  t_act[SPT];
    float t_x[SPT], t_y[SPT], t_z[SPT];  // real coords
    int loc = 0, loc_t = 0;
    #pragma unroll
    for (int s = 0; s < SPT; ++s) {
        const int n = tid + NTH * s;
        const float gz = (float)(n >> 10);
        const float gx = (float)((n >> 5) & 31);
        const float gy = (float)(n & 31);
        float conf = 1.0f / (1.0f + expf(-pf0[s].x));   // jax.nn.sigmoid
        bool a = conf > 0.5f;
        act[s] = a;
        loc += a ? 1 : 0;
        unsigned int u = ~(__float_as_uint(conf) | 0x80000000u);  // conf desc
        key[s] = a ? (((unsigned long long)u << 32) | (unsigned int)n)  // idx asc
                   : ~0ull;
        cx[s] = (pf0[s].y + gz) * 0.25f;
        cy[s] = (pf1[s].x + gx) * 0.03125f;
        cz[s] = (pf1[s].y + gy) * 0.03125f;
        bool ta = tf0[s].x > 0.5f;
        t_act[s] = ta;
        loc_t += ta ? 1 : 0;
        t_x[s] = (tf0[s].y + gz) * 6.25f;      // /4 * 25
        t_y[s] = (tf1[s].x + gx) * 0.78125f;   // /32 * 25
        t_z[s] = (tf1[s].y + gy) * 0.125f;     // /32 * 4
    }

    // ---- NMS fixpoint (exact reference trajectory, order via keys) ----
    int cur = blockReduceSumI(loc, scr_i, tid);
    int prev = -1;
    bool small_done = false;
    int n_pd = 0;
    while (cur != prev) {
        if (cur <= 64) {
            // ---- compact survivors; wave 0 finishes fixpoint in-wave ----
            if (tid == 0) cnt[2] = 0;
            __syncthreads();
            #pragma unroll
            for (int s = 0; s < SPT; ++s) {
                if (act[s]) {
                    int e = atomicAdd(&cnt[2], 1);
                    u_key[e] = key[s]; u_x[e] = cx[s]; u_y[e] = cy[s]; u_z[e] = cz[s];
                }
            }
            __syncthreads();
            if (tid < 64) {
                const int n = cnt[2];   // == cur
                bool va = tid < n;
                unsigned long long k = va ? u_key[tid] : ~0ull;
                float x = va ? u_x[tid] : 0.f;
                float y = va ? u_y[tid] : 0.f;
                float z = va ? u_z[tid] : 0.f;
                bool a = va;
                int pc = prev, cc = cur;
                while (cc != pc) {
                    unsigned long long am = __ballot(a);
                    // pass 1: s[j] = exists active i, key_i<key_j, d<cutoff
                    bool sfl = false;
                    for (int i = 0; i < n; ++i) {
                        unsigned long long ki = __shfl(k, i, 64);
                        float xi = __shfl(x, i, 64);
                        float yi = __shfl(y, i, 64);
                        float zi = __shfl(z, i, 64);
                        if (((am >> i) & 1ull) && ki < k) {
                            float dx = xi - x, dy = yi - y, dz = zi - z;
                            if (dx * dx + dy * dy + dz * dz < 4.0f) sfl = true;
                        }
                    }
                    // pass 2: supp[j] = exists root u (active,!s), key_u<key_j
                    unsigned long long rm = __ballot(a && !sfl);
                    bool sp = false;
                    for (int i = 0; i < n; ++i) {
                        if ((rm >> i) & 1ull) {
                            unsigned long long ki = __shfl(k, i, 64);
                            float xi = __shfl(x, i, 64);
                            float yi = __shfl(y, i, 64);
                            float zi = __shfl(z, i, 64);
                            if (ki < k) {
                                float dx = xi - x, dy = yi - y, dz = zi - z;
                                if (dx * dx + dy * dy + dz * dz < 4.0f) sp = true;
                            }
                        }
                    }
                    a = a && !sp;
                    pc = cc;
                    cc = __popcll(__ballot(a));
                }
                // write keep-list directly (order irrelevant for results)
                unsigned long long fm = __ballot(a);
                int K = __popcll(fm);
                if (tid == 0) { cnt[3] = K; cnt[0] = K; }
                if (a) {
                    int e = __popcll(fm & ((1ull << tid) - 1ull));
                    k_x[e] = x * 25.0f; k_y[e] = y * 25.0f; k_z[e] = z * 4.0f;
                    k_idx[e] = (int)(k & 0xFFFFFFFFull);
                    k_match[e] = 0xFFFFFFFFu;
                }
            }
            __syncthreads();
            n_pd = cnt[0];
            small_done = true;
            break;
        }

        // ---- cooperative step (large active set) ----
        // filter = per-wave confidence champion (min key among actives)
        {
            unsigned long long bk = ~0ull;
            float bx = 0.f, by = 0.f, bz = 0.f;
            #pragma unroll
            for (int s = 0; s < SPT; ++s)
                if (act[s] && key[s] < bk) { bk = key[s]; bx = cx[s]; by = cy[s]; bz = cz[s]; }
            #pragma unroll
            for (int o = 32; o > 0; o >>= 1) {
                unsigned long long ok = __shfl_xor(bk, o, 64);
                float ox = __shfl_xor(bx, o, 64);
                float oy = __shfl_xor(by, o, 64);
                float oz = __shfl_xor(bz, o, 64);
                if (ok < bk) { bk = ok; bx = ox; by = oy; bz = oz; }
            }
            if ((tid & 63) == 0) {
                int w = tid >> 6;
                f_key[w] = bk; f_x[w] = bx; f_y[w] = by; f_z[w] = bz;
            }
        }
        __syncthreads();

        // pass 1: s[j] = exists active i (key_i<key_j) within cutoff
        bool sflag[SPT], pend[SPT];
        #pragma unroll
        for (int s = 0; s < SPT; ++s) {
            sflag[s] = false; pend[s] = false;
            if (!act[s]) continue;
            bool found = false;
            for (int f = 0; f < NFILT; ++f) {
                if (f_key[f] < key[s]) {
                    float dx = f_x[f] - cx[s], dy = f_y[f] - cy[s], dz = f_z[f] - cz[s];
                    if (dx * dx + dy * dy + dz * dz < 4.0f) { found = true; break; }
                }
            }
            if (found) sflag[s] = true;
            else pend[s] = true;
        }
        // single-shot cooperative resolve (overflow loops only if cnt > MAXQ)
        do {
            if (tid == 0) cnt[1] = 0;
            __syncthreads();   // fences prior q_* reads vs rewrites
            int qe[SPT];
            #pragma unroll
            for (int s = 0; s < SPT; ++s) {
                qe[s] = -1;
                if (pend[s]) {
                    int e = atomicAdd(&cnt[1], 1);
                    if (e < MAXQ) {
                        q_key[e] = key[s]; q_x[e] = cx[s]; q_y[e] = cy[s]; q_z[e] = cz[s];
                        q_res[e] = 0;
                        qe[s] = e; pend[s] = false;
                    }
                }
            }
            __syncthreads();
            const int Q = min(cnt[1], MAXQ);
            for (int e = 0; e < Q; ++e) {     // uniform loop
                unsigned long long qk = q_key[e];
                float qx = q_x[e], qy = q_y[e], qz = q_z[e];
                bool hit = false;
                #pragma unroll
                for (int s = 0; s < SPT; ++s) {
                    if (act[s] && key[s] < qk) {
                        float dx = cx[s] - qx, dy = cy[s] - qy, dz = cz[s] - qz;
                        if (dx * dx + dy * dy + dz * dz < 4.0f) hit = true;
                    }
                }
                if (hit) q_res[e] = 1;        // benign race: all writers store 1
            }
            __syncthreads();
            #pragma unroll
            for (int s = 0; s < SPT; ++s)
                if (qe[s] >= 0) sflag[s] = (q_res[qe[s]] != 0);
        } while (cnt[1] > MAXQ);

        // pass 2: supp[j] = exists u in U={active,!s} with key_u<key_j, d<cutoff
        bool upend[SPT], supp[SPT];
        #pragma unroll
        for (int s = 0; s < SPT; ++s) {
            upend[s] = act[s] && !sflag[s];
            supp[s] = false;
        }
        do {
            if (tid == 0) cnt[2] = 0;
            __syncthreads();   // fences prior u_* reads vs rewrites
            #pragma unroll
            for (int s = 0; s < SPT; ++s) {
                if (upend[s]) {
                    int e = atomicAdd(&cnt[2], 1);
                    if (e < MAXU) {
                        u_key[e] = key[s]; u_x[e] = cx[s]; u_y[e] = cy[s]; u_z[e] = cz[s];
                        upend[s] = false;
                    }
                }
            }
            __syncthreads();
            const int Ku = min(cnt[2], MAXU);
            #pragma unroll
            for (int s = 0; s < SPT; ++s) {
                if (!act[s] || supp[s]) continue;
                for (int e = 0; e < Ku; ++e) {
                    if (u_key[e] < key[s]) {
                        float dx = u_x[e] - cx[s], dy = u_y[e] - cy[s], dz = u_z[e] - cz[s];
                        if (dx * dx + dy * dy + dz * dz < 4.0f) { supp[s] = true; break; }
                    }
                }
            }
        } while (cnt[2] > MAXU);
        // commit
        loc = 0;
        #pragma unroll
        for (int s = 0; s < SPT; ++s) {
            if (act[s] && supp[s]) act[s] = false;
            loc += act[s] ? 1 : 0;
        }
        prev = cur;
        cur = blockReduceSumI(loc, scr_i, tid);
    }
    if (!small_done) n_pd = cur;

    // ---- matching: kept preds vs all targets, lowest target idx wins ----
    bool kpend[SPT];
    #pragma unroll
    for (int s = 0; s < SPT; ++s) kpend[s] = small_done ? false : act[s];
    int loc_tp = 0;
    float loc_ang = 0.0f;
    do {
        if (tid == 0 && !small_done) cnt[3] = 0;
        __syncthreads();   // fences prior k_* reads vs rewrites
        #pragma unroll
        for (int s = 0; s < SPT; ++s) {
            if (kpend[s]) {
                int e = atomicAdd(&cnt[3], 1);
                if (e < MAXK) {
                    k_x[e] = cx[s] * 25.0f; k_y[e] = cy[s] * 25.0f; k_z[e] = cz[s] * 4.0f;
                    k_idx[e] = tid + NTH * s;
                    k_match[e] = 0xFFFFFFFFu;
                    kpend[s] = false;
                }
            }
        }
        __syncthreads();
        const int K = min(cnt[3], MAXK);
        #pragma unroll
        for (int s = 0; s < SPT; ++s) {
            if (!t_act[s]) continue;
            float tx = t_x[s], ty = t_y[s], tz = t_z[s];
            for (int e = 0; e < K; ++e) {
                float dx = tx - k_x[e], dy = ty - k_y[e], dz = tz - k_z[e];
                if (dx * dx + dy * dy + dz * dz < 4.0f)
                    atomicMin(&k_match[e], (unsigned int)(tid + NTH * s));  // few hits
            }
        }
        __syncthreads();
        if (tid < K) {
            unsigned int m = k_match[tid];
            if (m != 0xFFFFFFFFu) {
                ++loc_tp;
                const float2* pr = (const float2*)(pb + (size_t)k_idx[tid] * 10 + 4);
                float2 p0 = pr[0], p1 = pr[1], p2v = pr[2];
                float ax0 = p0.x, ax1 = p0.y, ax2 = p1.x;
                float ay0 = p1.y, ay1 = p2v.x, ay2 = p2v.y;
                float az0 = ax1 * ay2 - ax2 * ay1;
                float az1 = ax2 * ay0 - ax0 * ay2;
                float az2 = ax0 * ay1 - ax1 * ay0;
                const float2* tr = (const float2*)(tb + (size_t)m * 10 + 4);
                float2 t0 = tr[0], t1 = tr[1], t2v = tr[2];
                float bx0 = t0.x, bx1 = t0.y, bx2 = t1.x;
                float by0 = t1.y, by1 = t2v.x, by2 = t2v.y;
                float bz0 = bx1 * by2 - bx2 * by1;
                float bz1 = bx2 * by0 - bx0 * by2;
                float bz2 = bx0 * by1 - bx1 * by0;
                loc_ang += rowAngleDeg(ax0, ax1, ax2, bx0, bx1, bx2);
                loc_ang += rowAngleDeg(ay0, ay1, ay2, by0, by1, by2);
                loc_ang += rowAngleDeg(az0, az1, az2, bz0, bz1, bz2);
            }
        }
    } while (cnt[3] > MAXK);

    // ---- fused final reduce: tp (int), n_targ (int), angle (float) ----
    {
        int v0 = loc_tp, v1 = loc_t;
        float vf = loc_ang;
        #pragma unroll
        for (int o = 32; o > 0; o >>= 1) {
            v0 += __shfl_down(v0, o, 64);
            v1 += __shfl_down(v1, o, 64);
            vf += __shfl_down(vf, o, 64);
        }
        if ((tid & 63) == 0) {
            int w = tid >> 6;
            scr_i[w] = v0; scr_i[16 + w] = v1; scr_f[w] = vf;
        }
        __syncthreads();
        if (tid == 0) {
            int tp = 0, nt = 0;
            float angsum = 0.0f;
            #pragma unroll
            for (int w = 0; w < NTH / 64; ++w) {
                tp += scr_i[w]; nt += scr_i[16 + w]; angsum += scr_f[w];
            }
            out[b * 3 + 0] = (float)tp;
            out[b * 3 + 1] = (float)(n_pd - tp);
            out[b * 3 + 2] = (float)(nt - tp);
            out[NB * 3 + b] = (tp > 0) ? (angsum / (3.0f * (float)tp)) : 0.0f;
        }
    }
}

extern "C" void kernel_launch(void* const* d_in, const int* in_sizes, int n_in,
                              void* d_out, int out_size, void* d_ws, size_t ws_size,
                              hipStream_t stream) {
    const float* pred = (const float*)d_in[0];
    const float* targ = (const float*)d_in[1];
    float* out = (float*)d_out;
    (void)d_ws; (void)ws_size;
    molan_fused<<<dim3(NB), dim3(NTH), 0, stream>>>(pred, targ, out);
}